// Round 6
// baseline (201.210 us; speedup 1.0000x reference)
//
#include <hip/hip_runtime.h>
#include <hip/hip_bf16.h>
#include <stdint.h>

using bf16 = __hip_bfloat16;
typedef __attribute__((ext_vector_type(8))) short   short8;
typedef __attribute__((ext_vector_type(4))) float   floatx4;
typedef __attribute__((ext_vector_type(2))) unsigned int uint2v;

static __device__ __forceinline__ unsigned short f2bf(float f) {
    return __builtin_bit_cast(unsigned short, __float2bfloat16(f));
}

// 8 consecutive elements at element-offset e as packed bf16 (f=1: fp32 cvt).
static __device__ __forceinline__ uint4 load8bf(const void* p, size_t e, int f) {
    if (!f) return *(const uint4*)((const ushort*)p + e);
    const float* fp = (const float*)p + e;
    float4 a = *(const float4*)fp;
    float4 b = *(const float4*)(fp + 4);
    union { uint4 u; unsigned short s[8]; } r;
    r.s[0] = f2bf(a.x); r.s[1] = f2bf(a.y); r.s[2] = f2bf(a.z); r.s[3] = f2bf(a.w);
    r.s[4] = f2bf(b.x); r.s[5] = f2bf(b.y); r.s[6] = f2bf(b.z); r.s[7] = f2bf(b.w);
    return r.u;
}
static __device__ __forceinline__ float loadScalar(const void* p, int i, int f) {
    return f ? ((const float*)p)[i] : __bfloat162float(((const bf16*)p)[i]);
}

// async global->LDS, width 16B.  Per-lane global src, wave-uniform LDS base
// (HW writes base + lane*16).
#define GLL16(g, l)                                                          \
    __builtin_amdgcn_global_load_lds(                                        \
        (const __attribute__((address_space(1))) void*)(g),                  \
        (__attribute__((address_space(3))) void*)(l), 16, 0, 0)

// ---------------------------------------------------------------------------
__global__ void detect_dtype(const ushort* __restrict__ x, int* __restrict__ flag) {
    __shared__ int cnt;
    if (threadIdx.x == 0) cnt = 0;
    __syncthreads();
    unsigned short u = x[threadIdx.x * 2];
    int e = (u >> 7) & 0xFF;
    int bad = (e > 133 || e < 94) ? 1 : 0;
    atomicAdd(&cnt, bad);
    __syncthreads();
    if (threadIdx.x == 0) *flag = (cnt > 64) ? 1 : 0;
}

// ---------------------------------------------------------------------------
// One-shot bf16 conversion of x (4Mi), Wq/Wk/Wv/Wo (1Mi each) into a packed
// 8Mi-elem workspace region.  f=0: plain copy.
// ---------------------------------------------------------------------------
__global__ void cvt_bf16(const void* __restrict__ x,  const void* __restrict__ Wq,
                         const void* __restrict__ Wk, const void* __restrict__ Wv,
                         const void* __restrict__ Wo,
                         ushort* __restrict__ out, const int* __restrict__ flagp)
{
    const int f = *flagp;
    const size_t M1 = (size_t)1 << 20, M4 = (size_t)4 << 20;
    size_t i = ((size_t)blockIdx.x * 256 + threadIdx.x) * 8;
    const void* src; size_t off;
    if (i < M4)            { src = x;  off = i; }
    else if (i < M4 + M1)  { src = Wq; off = i - M4; }
    else if (i < M4 + 2*M1){ src = Wk; off = i - (M4 + M1); }
    else if (i < M4 + 3*M1){ src = Wv; off = i - (M4 + 2*M1); }
    else                   { src = Wo; off = i - (M4 + 3*M1); }
    *(uint4*)(out + i) = load8bf(src, off, f);
}

// ---------------------------------------------------------------------------
// R21 primary GEMM: bf16 A/W, global_load_lds width-16 staging with
// DOUBLE-buffered LDS + COUNTED vmcnt (T3/T4 "minimum 2-phase").
// R20's loop was GLL;__syncthreads() — the implicit vmcnt(0) barrier drain
// exposed full L2/HBM latency every K-iter (zero overlap).  Now tile t+1's
// 3 loads are issued BEFORE computing tile t; s_waitcnt vmcnt(3) keeps them
// in flight across the barrier, so their latency hides under 16 MFMAs.
// LDS 48 KB: As[2][128x64] @0, Ws[2][64x64] @16384 (ushort offsets).
// 2 raw s_barriers/iter, never vmcnt(0) until the last tile.
// pm/epilogues identical to before.
// ---------------------------------------------------------------------------
__global__ __launch_bounds__(512, 4)
void gemm_lds(const ushort* __restrict__ A,
              const ushort* __restrict__ Wa, const ushort* __restrict__ Wb2,
              const void* __restrict__ Ba, const void* __restrict__ Bb,
              void* __restrict__ Oa, void* __restrict__ Ob_,
              int pa, int pb, int out_ext, const int* __restrict__ flagp)
{
    __shared__ ushort pool[24576];   // 48 KB exactly (dbuf A + dbuf W)

    const int f  = *flagp;
    const int z  = blockIdx.z;
    const ushort* W  = z ? Wb2 : Wa;
    const void*  Bi  = z ? Bb : Ba;
    void*        Out = z ? Ob_ : Oa;
    const int    pm  = z ? pb : pa;

    const int m0 = blockIdx.x * 128;
    const int n0 = blockIdx.y * 64;
    const int tid  = threadIdx.x;
    const int lane = tid & 63;
    const int wave = tid >> 6;
    const int r15  = lane & 15;
    const int quad = lane >> 4;

    // staging geometry: lane l -> row base + (l>>3), slot l&7.
    // LDS slot s8 must hold global group s8 ^ (row&7)  (compute-read swizzle),
    // achieved by pre-swizzling the per-lane GLOBAL source (m173 pattern).
    const int l8 = lane >> 3, s8 = lane & 7;
    const int ar0 = wave * 16 + l8;         // A stage instr 0: rows w*16..+7
    const int ar1 = wave * 16 + 8 + l8;     // A stage instr 1: rows w*16+8..+15
    const int wr  = wave * 8 + l8;          // W stage: rows w*8..+7
    const ushort* gA0 = A + (size_t)(m0 + ar0) * 1024 + ((s8 ^ (ar0 & 7)) << 3);
    const ushort* gA1 = A + (size_t)(m0 + ar1) * 1024 + ((s8 ^ (ar1 & 7)) << 3);
    const ushort* gW  = W + (size_t)(n0 + wr) * 1024 + ((s8 ^ (wr & 7)) << 3);

    floatx4 acc[4];
#pragma unroll
    for (int db = 0; db < 4; db++) acc[db] = (floatx4){0.f, 0.f, 0.f, 0.f};

    // ---- prologue: stage tile 0 into buffer 0 ----
    GLL16(gA0, pool + wave * 1024);
    GLL16(gA1, pool + wave * 1024 + 512);
    GLL16(gW,  pool + 16384 + wave * 512);

    for (int kb = 0; kb < 1024; kb += 64) {
        const int cur = (kb >> 6) & 1;
        ushort* xs  = pool + cur * 8192;
        ushort* wsm = pool + 16384 + cur * 4096;
        if (kb + 64 < 1024) {
            ushort* xn = pool + (cur ^ 1) * 8192;
            ushort* wn = pool + 16384 + (cur ^ 1) * 4096;
            GLL16(gA0 + kb + 64, xn + wave * 1024);
            GLL16(gA1 + kb + 64, xn + wave * 1024 + 512);
            GLL16(gW  + kb + 64, wn + wave * 512);
            asm volatile("s_waitcnt vmcnt(3)" ::: "memory");  // tile t landed
        } else {
            asm volatile("s_waitcnt vmcnt(0)" ::: "memory");  // last tile
        }
        __builtin_amdgcn_s_barrier();        // all waves' tile-t loads landed
        __builtin_amdgcn_sched_barrier(0);   // no hoisting above the waitcnt
#pragma unroll
        for (int ks = 0; ks < 2; ks++) {
            int arow = wave * 16 + r15;
            short8 af = *(const short8*)(
                &xs[arow * 64 + (((ks * 4 + quad) ^ (arow & 7)) << 3)]);
#pragma unroll
            for (int db = 0; db < 4; db++) {
                int brow = db * 16 + r15;
                short8 bv = *(const short8*)(
                    &wsm[brow * 64 + (((ks * 4 + quad) ^ (brow & 7)) << 3)]);
                acc[db] = __builtin_amdgcn_mfma_f32_16x16x32_bf16(
                    af, bv, acc[db], 0, 0, 0);
            }
        }
        __builtin_amdgcn_s_barrier();  // reads of buf done before t+2's DMA
    }

    // C/D layout: col = lane&15, row = quad*4 + r (m89/m91)
    if (pm == 2) {
        // ---- V^T epilogue: acc -> LDS T[64 d][128 s] (swizzled) -> global ----
#pragma unroll
        for (int db = 0; db < 4; db++) {
            int d = db * 16 + r15;
            float bias = loadScalar(Bi, n0 + d, f);
            int s4 = wave * 16 + quad * 4;
            union { uint2 u; ushort us[4]; } pk;
#pragma unroll
            for (int r = 0; r < 4; r++) pk.us[r] = f2bf(acc[db][r] + bias);
            *(uint2*)(&pool[d * 128 + (((s4 >> 3) ^ (d & 15)) << 3) + (s4 & 7)])
                = pk.u;
        }
        __syncthreads();
        const int b_  = m0 >> 11;
        const int h   = n0 >> 6;
        const int sl0 = m0 & 2047;
#pragma unroll
        for (int rr = 0; rr < 2; rr++) {
            int idx = rr * 512 + tid;
            int d = idx >> 4, sgrp = idx & 15;
            uint4 v = *(const uint4*)(&pool[d * 128 + ((sgrp ^ (d & 15)) << 3)]);
            *(uint4*)((ushort*)Out +
                      ((size_t)((b_ * 16 + h) * 64 + d) << 11) + sl0 + sgrp * 8) = v;
        }
        return;
    }

#pragma unroll
    for (int db = 0; db < 4; db++) {
        int col = n0 + db * 16 + r15;
        float bias = loadScalar(Bi, col, f);
#pragma unroll
        for (int r = 0; r < 4; r++) {
            int row = m0 + wave * 16 + quad * 4 + r;
            float v = acc[db][r] + bias;
            if (pm == 1) {
                int hh = col >> 6, d = col & 63;
                int b_ = row >> 11, s = row & 2047;
                ((ushort*)Out)[(((size_t)(b_ * 16 + hh) * 2048 + s) << 6) + d]
                    = f2bf(v);
            } else if (out_ext && f) {
                ((float*)Out)[(size_t)row * 1024 + col] = v;
            } else {
                ((ushort*)Out)[(size_t)row * 1024 + col] = f2bf(v);
            }
        }
    }
}

// ---------------------------------------------------------------------------
// Fallback GEMM (reg-staged, dual-dtype) — used only when workspace is too
// small for the cvt path.  Identical to R19.
// ---------------------------------------------------------------------------
template<int BM>
__global__ __launch_bounds__(512, 4)
void gemm_bt(const void* __restrict__ A,
             const void* __restrict__ Wa, const void* __restrict__ Wb,
             const void* __restrict__ Ba, const void* __restrict__ Bb,
             void* __restrict__ Oa, void* __restrict__ Ob_,
             int pa, int pb, int a_ext, int out_ext,
             const int* __restrict__ flagp)
{
    constexpr int MB = BM / 128;
    constexpr int P  = BM / 64;
    constexpr int SG = BM / 8;
    __shared__ ushort pool[BM * 64 + 4096];

    const int f  = *flagp;
    const int fA = a_ext ? f : 0;
    const int z  = blockIdx.z;
    const void* W   = z ? Wb : Wa;
    const void* Bi  = z ? Bb : Ba;
    void*       Out = z ? Ob_ : Oa;
    const int   pm  = z ? pb : pa;

    const int m0 = blockIdx.x * BM;
    const int n0 = blockIdx.y * 64;
    const int tid  = threadIdx.x;
    const int lane = tid & 63;
    const int wave = tid >> 6;
    const int r15  = lane & 15;
    const int quad = lane >> 4;

    const int srow = tid >> 3;
    const int sg   = tid & 7;

    ushort* xs  = pool;
    ushort* wsm = pool + BM * 64;

    floatx4 acc[MB][4];
#pragma unroll
    for (int mb = 0; mb < MB; mb++)
#pragma unroll
        for (int db = 0; db < 4; db++) acc[mb][db] = (floatx4){0.f, 0.f, 0.f, 0.f};

    uint4 apre[P], wpre;
#pragma unroll
    for (int p = 0; p < P; p++)
        apre[p] = load8bf(A, (size_t)(m0 + srow + p * 64) * 1024 + sg * 8, fA);
    wpre = load8bf(W, (size_t)(n0 + srow) * 1024 + sg * 8, f);

    for (int kb = 0; kb < 1024; kb += 64) {
#pragma unroll
        for (int p = 0; p < P; p++) {
            int row = srow + p * 64;
            *(uint4*)(&xs[row * 64 + ((sg ^ (row & 7)) << 3)]) = apre[p];
        }
        *(uint4*)(&wsm[srow * 64 + ((sg ^ (srow & 7)) << 3)]) = wpre;
        __syncthreads();
        if (kb + 64 < 1024) {
#pragma unroll
            for (int p = 0; p < P; p++)
                apre[p] = load8bf(A, (size_t)(m0 + srow + p * 64) * 1024
                                      + kb + 64 + sg * 8, fA);
            wpre = load8bf(W, (size_t)(n0 + srow) * 1024 + kb + 64 + sg * 8, f);
        }
#pragma unroll
        for (int ks = 0; ks < 2; ks++) {
            short8 af[MB];
#pragma unroll
            for (int mb = 0; mb < MB; mb++) {
                int arow = wave * (16 * MB) + mb * 16 + r15;
                af[mb] = *(const short8*)(
                    &xs[arow * 64 + (((ks * 4 + quad) ^ (arow & 7)) << 3)]);
            }
#pragma unroll
            for (int db = 0; db < 4; db++) {
                int brow = db * 16 + r15;
                short8 bv = *(const short8*)(
                    &wsm[brow * 64 + (((ks * 4 + quad) ^ (brow & 7)) << 3)]);
#pragma unroll
                for (int mb = 0; mb < MB; mb++)
                    acc[mb][db] = __builtin_amdgcn_mfma_f32_16x16x32_bf16(
                        af[mb], bv, acc[mb][db], 0, 0, 0);
            }
        }
        __syncthreads();
    }

    if (pm == 2) {
#pragma unroll
        for (int mb = 0; mb < MB; mb++)
#pragma unroll
            for (int db = 0; db < 4; db++) {
                int d = db * 16 + r15;
                float bias = loadScalar(Bi, n0 + d, f);
                int s4 = wave * (16 * MB) + mb * 16 + quad * 4;
                union { uint2 u; ushort us[4]; } pk;
#pragma unroll
                for (int r = 0; r < 4; r++) pk.us[r] = f2bf(acc[mb][db][r] + bias);
                *(uint2*)(&pool[d * BM + (((s4 >> 3) ^ (d & 15)) << 3) + (s4 & 7)])
                    = pk.u;
            }
        __syncthreads();
        const int b_  = m0 >> 11;
        const int h   = n0 >> 6;
        const int sl0 = m0 & 2047;
#pragma unroll
        for (int rr = 0; rr < (64 * SG) / 512; rr++) {
            int idx = rr * 512 + tid;
            int d = idx / SG, sgrp = idx % SG;
            uint4 v = *(const uint4*)(&pool[d * BM + ((sgrp ^ (d & 15)) << 3)]);
            *(uint4*)((ushort*)Out +
                      ((size_t)((b_ * 16 + h) * 64 + d) << 11) + sl0 + sgrp * 8) = v;
        }
        return;
    }

#pragma unroll
    for (int mb = 0; mb < MB; mb++)
#pragma unroll
        for (int db = 0; db < 4; db++) {
            int col = n0 + db * 16 + r15;
            float bias = loadScalar(Bi, col, f);
#pragma unroll
            for (int r = 0; r < 4; r++) {
                int row = m0 + wave * (16 * MB) + mb * 16 + quad * 4 + r;
                float v = acc[mb][db][r] + bias;
                if (pm == 1) {
                    int hh = col >> 6, d = col & 63;
                    int b_ = row >> 11, s = row & 2047;
                    ((ushort*)Out)[(((size_t)(b_ * 16 + hh) * 2048 + s) << 6) + d]
                        = f2bf(v);
                } else if (out_ext && f) {
                    ((float*)Out)[(size_t)row * 1024 + col] = v;
                } else {
                    ((ushort*)Out)[(size_t)row * 1024 + col] = f2bf(v);
                }
            }
        }
}

// ---------------------------------------------------------------------------
// Fused Q-projection + flash attention (R19/R20 structure, measured 73 µs).
// Unchanged this round.
// ---------------------------------------------------------------------------
__global__ __launch_bounds__(512, 4)
void attn_fused(const void* __restrict__ x, const void* __restrict__ Wq,
                const void* __restrict__ bq,
                const ushort* __restrict__ K, const ushort* __restrict__ VT,
                ushort* __restrict__ AO, const int* __restrict__ flagp,
                int xisbf)
{
    __shared__ ushort pool[24576];          // 48 KB

    const int f   = *flagp;
    const int fx  = xisbf ? 0 : f;          // x/Wq dtype in THIS dispatch
    const int bh  = blockIdx.x;
    const int h   = bh & 15, b_ = bh >> 4;
    const int q0  = blockIdx.y * 128;
    const int tid  = threadIdx.x;
    const int lane = tid & 63;
    const int wave = tid >> 6;
    const int qg   = wave >> 1;             // q-group: owns q rows qg*32..+31
    const int kh   = wave & 1;              // key half: keys kh*32..+31 of tile
    const int r15  = lane & 15;
    const int quad = lane >> 4;
    const size_t base = (size_t)bh << 17;

    const int srow = tid >> 3;
    const int sg   = tid & 7;

    // ---- early prefetch: flash tile 0 ----
    uint4 kpre = *(const uint4*)(K  + base + (size_t)srow * 64   + sg * 8);
    uint4 vpre = *(const uint4*)(VT + base + (size_t)srow * 2048 + sg * 8);

    // ---------------- Phase 1: Q tile (128 q x 64 d), pipelined ----------
    floatx4 qacc[4];
#pragma unroll
    for (int db = 0; db < 4; db++) qacc[db] = (floatx4){0.f,0.f,0.f,0.f};

    uint4 xpre[2], wpre;
#pragma unroll
    for (int p = 0; p < 2; p++)
        xpre[p] = load8bf(x, (size_t)(b_ * 2048 + q0 + srow + p * 64) * 1024
                              + sg * 8, fx);
    wpre = load8bf(Wq, (size_t)(h * 64 + srow) * 1024 + sg * 8, fx);

    for (int kb = 0; kb < 1024; kb += 64) {
        int buf = (kb >> 6) & 1;
        ushort* xs  = pool + buf * 8192;
        ushort* wsm = pool + 16384 + buf * 4096;
#pragma unroll
        for (int p = 0; p < 2; p++) {
            int row = srow + p * 64;
            *(uint4*)(&xs[row * 64 + ((sg ^ (row & 7)) << 3)]) = xpre[p];
        }
        *(uint4*)(&wsm[srow * 64 + ((sg ^ (srow & 7)) << 3)]) = wpre;
        __syncthreads();
        if (kb + 64 < 1024) {
#pragma unroll
            for (int p = 0; p < 2; p++)
                xpre[p] = load8bf(x, (size_t)(b_ * 2048 + q0 + srow + p * 64) * 1024
                                      + kb + 64 + sg * 8, fx);
            wpre = load8bf(Wq, (size_t)(h * 64 + srow) * 1024 + kb + 64 + sg * 8, fx);
        }
#pragma unroll
        for (int ks = 0; ks < 2; ks++) {
            int arow = wave * 16 + r15;
            short8 af = *(const short8*)(
                &xs[arow * 64 + (((ks * 4 + quad) ^ (arow & 7)) << 3)]);
#pragma unroll
            for (int db = 0; db < 4; db++) {
                int brow = db * 16 + r15;
                short8 bv = *(const short8*)(
                    &wsm[brow * 64 + (((ks * 4 + quad) ^ (brow & 7)) << 3)]);
                qacc[db] = __builtin_amdgcn_mfma_f32_16x16x32_bf16(
                    af, bv, qacc[db], 0, 0, 0);
            }
        }
    }

    // Qs overlays xs0 (last compute used xs1; own-wave rows only)
    ushort* Qs = pool;
    const float csc = 0.1803368801f;        // log2(e)/8
#pragma unroll
    for (int db = 0; db < 4; db++) {
        int d = db * 16 + r15;
        float bias = loadScalar(bq, h * 64 + d, f);
#pragma unroll
        for (int r = 0; r < 4; r++) {
            int q = wave * 16 + quad * 4 + r;
            Qs[q * 64 + (((d >> 3) ^ (q & 7)) << 3) + (d & 7)] =
                f2bf((qacc[db][r] + bias) * csc);
        }
    }
    __syncthreads();   // Qs visible to all waves (ownership remap)
    short8 qf2[2][2];
#pragma unroll
    for (int qb = 0; qb < 2; qb++)
#pragma unroll
        for (int ks = 0; ks < 2; ks++) {
            int arow = qg * 32 + qb * 16 + r15;
            qf2[qb][ks] = *(const short8*)(
                &Qs[arow * 64 + (((ks * 4 + quad) ^ (arow & 7)) << 3)]);
        }
    __syncthreads();   // qf2 loaded before pool reuse

    // ---------------- Phase 2: flash loop (1 barrier / tile) -------------
    floatx4 oacc[2][4], lacc[2];
#pragma unroll
    for (int qb = 0; qb < 2; qb++) {
#pragma unroll
        for (int db = 0; db < 4; db++) oacc[qb][db] = (floatx4){0.f,0.f,0.f,0.f};
        lacc[qb] = (floatx4){0.f,0.f,0.f,0.f};
    }
    short8 ones;
#pragma unroll
    for (int j = 0; j < 8; j++) ones[j] = (short)0x3F80;

    for (int t0 = 0; t0 < 2048; t0 += 64) {
        int buf = (t0 >> 6) & 1;
        ushort* Ks = pool + buf * 4096;
        ushort* Vt = pool + 8192 + buf * 4096;
        *(uint4*)(&Ks[srow * 64 + ((sg ^ (srow & 7)) << 3)]) = kpre;
        *(uint4*)(&Vt[srow * 64 + ((sg ^ (srow & 7)) << 3)]) = vpre;
        __syncthreads();
        if (t0 < 1984) {
            kpre = *(const uint4*)(K  + base + (size_t)(t0 + 64 + srow) * 64
                                       + sg * 8);
            vpre = *(const uint4*)(VT + base + (size_t)srow * 2048
                                       + t0 + 64 + sg * 8);
        }

        // S^T = K Q^T : rows = own 32 keys (kh half), cols = own 32 queries
        floatx4 s[2][2];
#pragma unroll
        for (int mb = 0; mb < 2; mb++)
#pragma unroll
            for (int qb = 0; qb < 2; qb++) s[mb][qb] = (floatx4){0.f,0.f,0.f,0.f};
#pragma unroll
        for (int ks = 0; ks < 2; ks++)
#pragma unroll
            for (int mb = 0; mb < 2; mb++) {
                int arow = kh * 32 + mb * 16 + r15;
                short8 kf = *(const short8*)(
                    &Ks[arow * 64 + (((ks * 4 + quad) ^ (arow & 7)) << 3)]);
#pragma unroll
                for (int qb = 0; qb < 2; qb++)
                    s[mb][qb] = __builtin_amdgcn_mfma_f32_16x16x32_bf16(
                        kf, qf2[qb][ks], s[mb][qb], 0, 0, 0);
            }

        // P = 2^S, truncation-packed bf16 pairs in-register
        uint Lr[2][2], Hr[2][2];
#pragma unroll
        for (int mb = 0; mb < 2; mb++)
#pragma unroll
            for (int qb = 0; qb < 2; qb++) {
                uint b0 = __builtin_bit_cast(uint, __builtin_amdgcn_exp2f(s[mb][qb][0]));
                uint b1 = __builtin_bit_cast(uint, __builtin_amdgcn_exp2f(s[mb][qb][1]));
                uint b2 = __builtin_bit_cast(uint, __builtin_amdgcn_exp2f(s[mb][qb][2]));
                uint b3 = __builtin_bit_cast(uint, __builtin_amdgcn_exp2f(s[mb][qb][3]));
                Lr[mb][qb] = (b1 & 0xFFFF0000u) | (b0 >> 16);
                Hr[mb][qb] = (b3 & 0xFFFF0000u) | (b2 >> 16);
            }
        // Quad-transpose via permlane{32,16}_swap (R18-verified mapping)
        short8 pf[2];
#pragma unroll
        for (int qb = 0; qb < 2; qb++) {
            uint2v tL = __builtin_amdgcn_permlane32_swap(
                Lr[0][qb], Lr[1][qb], false, false);
            uint2v uL = __builtin_amdgcn_permlane16_swap(
                tL[0], tL[1], false, false);
            uint2v tH = __builtin_amdgcn_permlane32_swap(
                Hr[0][qb], Hr[1][qb], false, false);
            uint2v uH = __builtin_amdgcn_permlane16_swap(
                tH[0], tH[1], false, false);
            union { uint u[4]; short8 s8; } pk;
            pk.u[0] = uL[0]; pk.u[1] = uH[0]; pk.u[2] = uL[1]; pk.u[3] = uH[1];
            pf[qb] = pk.s8;
        }

        // O += P V^T (own key half = k-slice kh), l += P·1
#pragma unroll
        for (int db = 0; db < 4; db++) {
            int brow = db * 16 + r15;
            short8 vf = *(const short8*)(
                &Vt[brow * 64 + (((kh * 4 + quad) ^ (brow & 7)) << 3)]);
#pragma unroll
            for (int qb = 0; qb < 2; qb++)
                oacc[qb][db] = __builtin_amdgcn_mfma_f32_16x16x32_bf16(
                    pf[qb], vf, oacc[qb][db], 0, 0, 0);
        }
#pragma unroll
        for (int qb = 0; qb < 2; qb++)
            lacc[qb] = __builtin_amdgcn_mfma_f32_16x16x32_bf16(
                pf[qb], ones, lacc[qb], 0, 0, 0);
    }

    // ---- kh-pair reduction (f32, via LDS) + epilogue -> AO ----
    __syncthreads();
    {
        char* rb = (char*)pool + qg * 10240 + lane * 16;
        if (kh) {
#pragma unroll
            for (int qb = 0; qb < 2; qb++) {
#pragma unroll
                for (int db = 0; db < 4; db++)
                    *(floatx4*)(rb + (qb * 4 + db) * 1024) = oacc[qb][db];
                *(floatx4*)(rb + (8 + qb) * 1024) = lacc[qb];
            }
        }
        __syncthreads();
        if (!kh) {
#pragma unroll
            for (int qb = 0; qb < 2; qb++) {
#pragma unroll
                for (int db = 0; db < 4; db++)
                    oacc[qb][db] += *(const floatx4*)(rb + (qb * 4 + db) * 1024);
                lacc[qb] += *(const floatx4*)(rb + (8 + qb) * 1024);
            }
            float inv[2][4];
#pragma unroll
            for (int qb = 0; qb < 2; qb++)
#pragma unroll
                for (int r = 0; r < 4; r++) inv[qb][r] = 1.f / lacc[qb][r];
#pragma unroll
            for (int qb = 0; qb < 2; qb++)
#pragma unroll
                for (int db = 0; db < 4; db++) {
                    int d = db * 16 + r15;
#pragma unroll
                    for (int r = 0; r < 4; r++) {
                        int qi = q0 + qg * 32 + qb * 16 + quad * 4 + r;
                        AO[((size_t)(b_ * 2048 + qi) << 10) + h * 64 + d] =
                            f2bf(oacc[qb][db][r] * inv[qb][r]);
                    }
                }
        }
    }
}

__global__ void copy_u4(const uint4* __restrict__ src, uint4* __restrict__ dst) {
    size_t i = (size_t)blockIdx.x * 256 + threadIdx.x;
    dst[i] = src[i];
}

// ---------------------------------------------------------------------------
extern "C" void kernel_launch(void* const* d_in, const int* in_sizes, int n_in,
                              void* d_out, int out_size, void* d_ws, size_t ws_size,
                              hipStream_t stream)
{
    const void* x  = d_in[0];
    const void* Wq = d_in[1];
    const void* bq = d_in[2];
    const void* Wk = d_in[3];
    const void* bk = d_in[4];
    const void* Wv = d_in[5];
    const void* bv = d_in[6];
    const void* Wo = d_in[7];
    const void* bo = d_in[8];

    const size_t TEN = (size_t)2 * 16 * 2048 * 64;   // 4 Mi elements (8 MB)
    const size_t M1  = (size_t)1 << 20;
    int*    flagp = (int*)d_ws;
    ushort* Kw    = (ushort*)((char*)d_ws + 256);
    ushort* Vw    = Kw + TEN;

    // ws tiers:
    //   >= 40.25 MB : cvt path + AOw in ws
    //   >= 32.25 MB : cvt path, AOw = d_out (+copy dance)
    //   >= 24.25 MB : legacy big_ws path
    //   else        : legacy small_ws path
    const size_t need_cvt = 256 + (2 * TEN + 8 * M1) * sizeof(ushort);
    const size_t need_aow = need_cvt + TEN * sizeof(ushort);

    detect_dtype<<<1, 256, 0, stream>>>((const ushort*)x, flagp);

    if (ws_size >= need_cvt) {
        ushort* CV  = Vw + TEN;
        ushort* xb  = CV;
        ushort* wqb = CV + 4 * M1;
        ushort* wkb = CV + 5 * M1;
        ushort* wvb = CV + 6 * M1;
        ushort* wob = CV + 7 * M1;
        const bool aow_ws = ws_size >= need_aow;
        ushort* AOw = aow_ws ? (CV + 8 * M1) : (ushort*)d_out;
        ushort* Oin = aow_ws ? AOw : Kw;

        // one-shot bf16 conversion of x + all weights (8 Mi elems)
        cvt_bf16<<<dim3(4096), dim3(256), 0, stream>>>(
            x, Wq, Wk, Wv, Wo, CV, flagp);

        // K -> Kw [B,H,S,D] (pm=1) and V -> Vw [B,H,D,S] (pm=2), gload_lds
        gemm_lds<<<dim3(32, 16, 2), dim3(512), 0, stream>>>(
            xb, wkb, wvb, bk, bv, Kw, Vw, /*pa=*/1, /*pb=*/2,
            /*out_ext=*/0, flagp);

        // fused Q-proj + attention (bf16 x/Wq)
        attn_fused<<<dim3(32, 16), dim3(512), 0, stream>>>(
            xb, wqb, bq, Kw, Vw, AOw, flagp, /*xisbf=*/1);

        if (!aow_ws)
            copy_u4<<<dim3(2048), dim3(256), 0, stream>>>(
                (const uint4*)d_out, (uint4*)Oin);

        // O-projection (A = attn output, already bf16)
        gemm_lds<<<dim3(32, 16, 1), dim3(512), 0, stream>>>(
            Oin, wob, wob, bo, bo, d_out, d_out, /*pa=*/0, /*pb=*/0,
            /*out_ext=*/1, flagp);
    } else {
        const bool big_ws = ws_size >= 3 * TEN * sizeof(ushort) + 256;
        ushort* AOw = big_ws ? (Vw + TEN) : (ushort*)d_out;
        ushort* Oin = big_ws ? AOw : Kw;

        gemm_bt<128><<<dim3(32, 16, 2), dim3(512), 0, stream>>>(
            x, Wk, Wv, bk, bv, Kw, Vw, 1, 2, 1, 0, flagp);
        attn_fused<<<dim3(32, 16), dim3(512), 0, stream>>>(
            x, Wq, bq, Kw, Vw, AOw, flagp, /*xisbf=*/0);
        if (!big_ws)
            copy_u4<<<dim3(2048), dim3(256), 0, stream>>>(
                (const uint4*)d_out, (uint4*)Oin);
        gemm_bt<128><<<dim3(32, 16, 1), dim3(512), 0, stream>>>(
            Oin, Wo, Wo, bo, bo, d_out, d_out, 0, 0, 0, 1, flagp);
    }
}

// Round 8
// 197.999 us; speedup vs baseline: 1.0162x; 1.0162x over previous
//
#include <hip/hip_runtime.h>
#include <hip/hip_bf16.h>
#include <stdint.h>

using bf16 = __hip_bfloat16;
typedef __attribute__((ext_vector_type(8))) short   short8;
typedef __attribute__((ext_vector_type(4))) float   floatx4;
typedef __attribute__((ext_vector_type(2))) unsigned int uint2v;

static __device__ __forceinline__ unsigned short f2bf(float f) {
    return __builtin_bit_cast(unsigned short, __float2bfloat16(f));
}

// 8 consecutive elements at element-offset e as packed bf16 (f=1: fp32 cvt).
static __device__ __forceinline__ uint4 load8bf(const void* p, size_t e, int f) {
    if (!f) return *(const uint4*)((const ushort*)p + e);
    const float* fp = (const float*)p + e;
    float4 a = *(const float4*)fp;
    float4 b = *(const float4*)(fp + 4);
    union { uint4 u; unsigned short s[8]; } r;
    r.s[0] = f2bf(a.x); r.s[1] = f2bf(a.y); r.s[2] = f2bf(a.z); r.s[3] = f2bf(a.w);
    r.s[4] = f2bf(b.x); r.s[5] = f2bf(b.y); r.s[6] = f2bf(b.z); r.s[7] = f2bf(b.w);
    return r.u;
}
static __device__ __forceinline__ float loadScalar(const void* p, int i, int f) {
    return f ? ((const float*)p)[i] : __bfloat162float(((const bf16*)p)[i]);
}

// async global->LDS, width 16B.  Per-lane global src, wave-uniform LDS base
// (HW writes base + lane*16).
#define GLL16(g, l)                                                          \
    __builtin_amdgcn_global_load_lds(                                        \
        (const __attribute__((address_space(1))) void*)(g),                  \
        (__attribute__((address_space(3))) void*)(l), 16, 0, 0)

// ---------------------------------------------------------------------------
__global__ void detect_dtype(const ushort* __restrict__ x, int* __restrict__ flag) {
    __shared__ int cnt;
    if (threadIdx.x == 0) cnt = 0;
    __syncthreads();
    unsigned short u = x[threadIdx.x * 2];
    int e = (u >> 7) & 0xFF;
    int bad = (e > 133 || e < 94) ? 1 : 0;
    atomicAdd(&cnt, bad);
    __syncthreads();
    if (threadIdx.x == 0) *flag = (cnt > 64) ? 1 : 0;
}

// ---------------------------------------------------------------------------
// One-shot bf16 conversion of x (4Mi), Wq/Wk/Wv/Wo (1Mi each) into a packed
// 8Mi-elem workspace region.  f=0: plain copy.
// ---------------------------------------------------------------------------
__global__ void cvt_bf16(const void* __restrict__ x,  const void* __restrict__ Wq,
                         const void* __restrict__ Wk, const void* __restrict__ Wv,
                         const void* __restrict__ Wo,
                         ushort* __restrict__ out, const int* __restrict__ flagp)
{
    const int f = *flagp;
    const size_t M1 = (size_t)1 << 20, M4 = (size_t)4 << 20;
    size_t i = ((size_t)blockIdx.x * 256 + threadIdx.x) * 8;
    const void* src; size_t off;
    if (i < M4)            { src = x;  off = i; }
    else if (i < M4 + M1)  { src = Wq; off = i - M4; }
    else if (i < M4 + 2*M1){ src = Wk; off = i - (M4 + M1); }
    else if (i < M4 + 3*M1){ src = Wv; off = i - (M4 + 2*M1); }
    else                   { src = Wo; off = i - (M4 + 3*M1); }
    *(uint4*)(out + i) = load8bf(src, off, f);
}

// ---------------------------------------------------------------------------
// R22/R23 dual-N GEMM: block tile 128m x 128n as TWO 64-col halves sharing
// one A-tile.  Half a: cols n0a of Wa -> Oa (mode pa); half b: cols n0b=
// n0a+nb_off of Wb -> Ob (mode pb).  KV proj: Wa=Wk, Wb=Wv, nb_off=0 -> ONE
// dispatch computes K and V off a single A staging (A traffic 384->256 MB,
// grid 1024->512 = one clean 2-blocks/CU round).  O-proj: Wa=Wb=Wo,
// nb_off=512, grid 32x8.
// Waves: wm=wave&3 owns 32 m-rows, wn=wave>>2 owns one 64-col half.
// Per iter/wave: 12 ds_read_b128 / 16 MFMA (0.75 ratio vs 1.25 before).
// Staging: global_load_lds w16, pre-swizzled global src (m173), dbuf 64 KB,
// counted vmcnt(4) (4 GLL16/wave in flight), 2 raw s_barriers/iter.
// pm per half: 0 row-major [M,1024]; 1 scatter bf16 [B,H,S,D];
//              2 V^T [B,H,D,S] via LDS transpose.
// ---------------------------------------------------------------------------
__global__ __launch_bounds__(512, 4)
void gemm_dual(const ushort* __restrict__ A,
               const ushort* __restrict__ Wa, const ushort* __restrict__ Wb2,
               const void* __restrict__ Ba, const void* __restrict__ Bb,
               void* __restrict__ Oa, void* __restrict__ Ob_,
               int pa, int pb, int nb_off, int out_ext,
               const int* __restrict__ flagp)
{
    __shared__ ushort pool[32768];   // 64 KB: As[2][128][64] @0, Ws[2][128][64] @16384

    const int f  = *flagp;
    const int m0 = blockIdx.x * 128;
    const int n0a = blockIdx.y * 64;
    const int n0b = n0a + nb_off;
    const int tid  = threadIdx.x;
    const int lane = tid & 63;
    const int wave = tid >> 6;
    const int wm   = wave & 3;              // m-slot: rows wm*32..+31
    const int wn   = wave >> 2;             // n-half: 0 = a, 1 = b
    const int r15  = lane & 15;
    const int quad = lane >> 4;

    const int   my_pm = wn ? pb : pa;
    const void* my_Bi = wn ? Bb : Ba;
    void*       my_O  = wn ? Ob_ : Oa;
    const int   my_n0 = wn ? n0b : n0a;

    // staging geometry: lane l -> combined row base + (l>>3), slot l&7.
    // LDS slot s8 holds global group s8 ^ (row&7) (pre-swizzled source).
    const int l8 = lane >> 3, s8 = lane & 7;
    const int ar0 = wave * 16 + l8;         // A rows: 0..127 across 8 waves
    const int ar1 = ar0 + 8;
    const int wr0 = wave * 16 + l8;         // W combined rows: 0..127
    const int wr1 = wr0 + 8;                // rows <64 -> Wa(n0a), >=64 -> Wb(n0b)
    const ushort* gA0 = A + (size_t)(m0 + ar0) * 1024 + ((s8 ^ (ar0 & 7)) << 3);
    const ushort* gA1 = A + (size_t)(m0 + ar1) * 1024 + ((s8 ^ (ar1 & 7)) << 3);
    const ushort* gW0 = (wr0 < 64 ? Wa + (size_t)(n0a + wr0) * 1024
                                  : Wb2 + (size_t)(n0b + wr0 - 64) * 1024)
                        + ((s8 ^ (wr0 & 7)) << 3);
    const ushort* gW1 = (wr1 < 64 ? Wa + (size_t)(n0a + wr1) * 1024
                                  : Wb2 + (size_t)(n0b + wr1 - 64) * 1024)
                        + ((s8 ^ (wr1 & 7)) << 3);

    floatx4 acc[2][4];
#pragma unroll
    for (int mb = 0; mb < 2; mb++)
#pragma unroll
        for (int db = 0; db < 4; db++) acc[mb][db] = (floatx4){0.f, 0.f, 0.f, 0.f};

    // ---- prologue: stage tile 0 into buffer 0 (4 GLL16 per wave) ----
    GLL16(gA0, pool + wave * 1024);
    GLL16(gA1, pool + wave * 1024 + 512);
    GLL16(gW0, pool + 16384 + wave * 1024);
    GLL16(gW1, pool + 16384 + wave * 1024 + 512);

    for (int kb = 0; kb < 1024; kb += 64) {
        const int cur = (kb >> 6) & 1;
        ushort* xs  = pool + cur * 8192;
        ushort* wsm = pool + 16384 + cur * 8192;
        if (kb + 64 < 1024) {
            ushort* xn = pool + (cur ^ 1) * 8192;
            ushort* wn_ = pool + 16384 + (cur ^ 1) * 8192;
            GLL16(gA0 + kb + 64, xn + wave * 1024);
            GLL16(gA1 + kb + 64, xn + wave * 1024 + 512);
            GLL16(gW0 + kb + 64, wn_ + wave * 1024);
            GLL16(gW1 + kb + 64, wn_ + wave * 1024 + 512);
            asm volatile("s_waitcnt vmcnt(4)" ::: "memory");  // tile t landed
        } else {
            asm volatile("s_waitcnt vmcnt(0)" ::: "memory");  // last tile
        }
        __builtin_amdgcn_s_barrier();        // all waves' tile-t loads landed
        __builtin_amdgcn_sched_barrier(0);   // no hoisting above the waitcnt
#pragma unroll
        for (int ks = 0; ks < 2; ks++) {
            short8 af[2];
#pragma unroll
            for (int mb = 0; mb < 2; mb++) {
                int arow = wm * 32 + mb * 16 + r15;
                af[mb] = *(const short8*)(
                    &xs[arow * 64 + (((ks * 4 + quad) ^ (arow & 7)) << 3)]);
            }
#pragma unroll
            for (int db = 0; db < 4; db++) {
                int brow = wn * 64 + db * 16 + r15;
                short8 bv = *(const short8*)(
                    &wsm[brow * 64 + (((ks * 4 + quad) ^ (brow & 7)) << 3)]);
#pragma unroll
                for (int mb = 0; mb < 2; mb++)
                    acc[mb][db] = __builtin_amdgcn_mfma_f32_16x16x32_bf16(
                        af[mb], bv, acc[mb][db], 0, 0, 0);
            }
        }
        __builtin_amdgcn_s_barrier();  // reads of buf done before t+2's DMA
    }

    // C/D layout: col = lane&15, row = quad*4 + r (m89/m91)
    if (my_pm == 2) {
        // ---- V^T: wn-half waves hold full 128s x 64d; -> LDS T -> global ----
#pragma unroll
        for (int mb = 0; mb < 2; mb++)
#pragma unroll
            for (int db = 0; db < 4; db++) {
                int d = db * 16 + r15;
                float bias = loadScalar(my_Bi, my_n0 + d, f);
                int s4 = wm * 32 + mb * 16 + quad * 4;
                union { uint2 u; ushort us[4]; } pk;
#pragma unroll
                for (int r = 0; r < 4; r++) pk.us[r] = f2bf(acc[mb][db][r] + bias);
                *(uint2*)(&pool[d * 128 + (((s4 >> 3) ^ (d & 15)) << 3) + (s4 & 7)])
                    = pk.u;
            }
    } else {
#pragma unroll
        for (int mb = 0; mb < 2; mb++)
#pragma unroll
            for (int db = 0; db < 4; db++) {
                int col = my_n0 + db * 16 + r15;
                float bias = loadScalar(my_Bi, col, f);
#pragma unroll
                for (int r = 0; r < 4; r++) {
                    int row = m0 + wm * 32 + mb * 16 + quad * 4 + r;
                    float v = acc[mb][db][r] + bias;
                    if (my_pm == 1) {
                        int hh = col >> 6, d = col & 63;
                        int b_ = row >> 11, s = row & 2047;
                        ((ushort*)my_O)[(((size_t)(b_ * 16 + hh) * 2048 + s) << 6) + d]
                            = f2bf(v);
                    } else if (out_ext && f) {
                        ((float*)my_O)[(size_t)row * 1024 + col] = v;
                    } else {
                        ((ushort*)my_O)[(size_t)row * 1024 + col] = f2bf(v);
                    }
                }
            }
    }

    // cooperative V^T store (uniform branch: pa/pb are scalar args)
    if (pa == 2 || pb == 2) {
        __syncthreads();
        void* OutT = (pb == 2) ? Ob_ : Oa;
        const int nT  = (pb == 2) ? n0b : n0a;
        const int b_  = m0 >> 11;
        const int h   = nT >> 6;
        const int sl0 = m0 & 2047;
#pragma unroll
        for (int rr = 0; rr < 2; rr++) {
            int idx = rr * 512 + tid;       // 0..1023 over 64d x 16 sgrp
            int d = idx >> 4, sgrp = idx & 15;
            uint4 v = *(const uint4*)(&pool[d * 128 + ((sgrp ^ (d & 15)) << 3)]);
            *(uint4*)((ushort*)OutT +
                      ((size_t)((b_ * 16 + h) * 64 + d) << 11) + sl0 + sgrp * 8) = v;
        }
    }
}

// ---------------------------------------------------------------------------
// Fallback GEMM (reg-staged, dual-dtype) — used only when workspace is too
// small for the cvt path.  Identical to R19.
// ---------------------------------------------------------------------------
template<int BM>
__global__ __launch_bounds__(512, 4)
void gemm_bt(const void* __restrict__ A,
             const void* __restrict__ Wa, const void* __restrict__ Wb,
             const void* __restrict__ Ba, const void* __restrict__ Bb,
             void* __restrict__ Oa, void* __restrict__ Ob_,
             int pa, int pb, int a_ext, int out_ext,
             const int* __restrict__ flagp)
{
    constexpr int MB = BM / 128;
    constexpr int P  = BM / 64;
    constexpr int SG = BM / 8;
    __shared__ ushort pool[BM * 64 + 4096];

    const int f  = *flagp;
    const int fA = a_ext ? f : 0;
    const int z  = blockIdx.z;
    const void* W   = z ? Wb : Wa;
    const void* Bi  = z ? Bb : Ba;
    void*       Out = z ? Ob_ : Oa;
    const int   pm  = z ? pb : pa;

    const int m0 = blockIdx.x * BM;
    const int n0 = blockIdx.y * 64;
    const int tid  = threadIdx.x;
    const int lane = tid & 63;
    const int wave = tid >> 6;
    const int r15  = lane & 15;
    const int quad = lane >> 4;

    const int srow = tid >> 3;
    const int sg   = tid & 7;

    ushort* xs  = pool;
    ushort* wsm = pool + BM * 64;

    floatx4 acc[MB][4];
#pragma unroll
    for (int mb = 0; mb < MB; mb++)
#pragma unroll
        for (int db = 0; db < 4; db++) acc[mb][db] = (floatx4){0.f, 0.f, 0.f, 0.f};

    uint4 apre[P], wpre;
#pragma unroll
    for (int p = 0; p < P; p++)
        apre[p] = load8bf(A, (size_t)(m0 + srow + p * 64) * 1024 + sg * 8, fA);
    wpre = load8bf(W, (size_t)(n0 + srow) * 1024 + sg * 8, f);

    for (int kb = 0; kb < 1024; kb += 64) {
#pragma unroll
        for (int p = 0; p < P; p++) {
            int row = srow + p * 64;
            *(uint4*)(&xs[row * 64 + ((sg ^ (row & 7)) << 3)]) = apre[p];
        }
        *(uint4*)(&wsm[srow * 64 + ((sg ^ (srow & 7)) << 3)]) = wpre;
        __syncthreads();
        if (kb + 64 < 1024) {
#pragma unroll
            for (int p = 0; p < P; p++)
                apre[p] = load8bf(A, (size_t)(m0 + srow + p * 64) * 1024
                                      + kb + 64 + sg * 8, fA);
            wpre = load8bf(W, (size_t)(n0 + srow) * 1024 + kb + 64 + sg * 8, f);
        }
#pragma unroll
        for (int ks = 0; ks < 2; ks++) {
            short8 af[MB];
#pragma unroll
            for (int mb = 0; mb < MB; mb++) {
                int arow = wave * (16 * MB) + mb * 16 + r15;
                af[mb] = *(const short8*)(
                    &xs[arow * 64 + (((ks * 4 + quad) ^ (arow & 7)) << 3)]);
            }
#pragma unroll
            for (int db = 0; db < 4; db++) {
                int brow = db * 16 + r15;
                short8 bv = *(const short8*)(
                    &wsm[brow * 64 + (((ks * 4 + quad) ^ (brow & 7)) << 3)]);
#pragma unroll
                for (int mb = 0; mb < MB; mb++)
                    acc[mb][db] = __builtin_amdgcn_mfma_f32_16x16x32_bf16(
                        af[mb], bv, acc[mb][db], 0, 0, 0);
            }
        }
        __syncthreads();
    }

    if (pm == 2) {
#pragma unroll
        for (int mb = 0; mb < MB; mb++)
#pragma unroll
            for (int db = 0; db < 4; db++) {
                int d = db * 16 + r15;
                float bias = loadScalar(Bi, n0 + d, f);
                int s4 = wave * (16 * MB) + mb * 16 + quad * 4;
                union { uint2 u; ushort us[4]; } pk;
#pragma unroll
                for (int r = 0; r < 4; r++) pk.us[r] = f2bf(acc[mb][db][r] + bias);
                *(uint2*)(&pool[d * BM + (((s4 >> 3) ^ (d & 15)) << 3) + (s4 & 7)])
                    = pk.u;
            }
        __syncthreads();
        const int b_  = m0 >> 11;
        const int h   = n0 >> 6;
        const int sl0 = m0 & 2047;
#pragma unroll
        for (int rr = 0; rr < (64 * SG) / 512; rr++) {
            int idx = rr * 512 + tid;
            int d = idx / SG, sgrp = idx % SG;
            uint4 v = *(const uint4*)(&pool[d * BM + ((sgrp ^ (d & 15)) << 3)]);
            *(uint4*)((ushort*)Out +
                      ((size_t)((b_ * 16 + h) * 64 + d) << 11) + sl0 + sgrp * 8) = v;
        }
        return;
    }

#pragma unroll
    for (int mb = 0; mb < MB; mb++)
#pragma unroll
        for (int db = 0; db < 4; db++) {
            int col = n0 + db * 16 + r15;
            float bias = loadScalar(Bi, col, f);
#pragma unroll
            for (int r = 0; r < 4; r++) {
                int row = m0 + wave * (16 * MB) + mb * 16 + quad * 4 + r;
                float v = acc[mb][db][r] + bias;
                if (pm == 1) {
                    int hh = col >> 6, d = col & 63;
                    int b_ = row >> 11, s = row & 2047;
                    ((ushort*)Out)[(((size_t)(b_ * 16 + hh) * 2048 + s) << 6) + d]
                        = f2bf(v);
                } else if (out_ext && f) {
                    ((float*)Out)[(size_t)row * 1024 + col] = v;
                } else {
                    ((ushort*)Out)[(size_t)row * 1024 + col] = f2bf(v);
                }
            }
        }
}

// ---------------------------------------------------------------------------
// Fused Q-projection + flash attention (R19/R20 structure, measured 73 µs).
// Unchanged this round.
// ---------------------------------------------------------------------------
__global__ __launch_bounds__(512, 4)
void attn_fused(const void* __restrict__ x, const void* __restrict__ Wq,
                const void* __restrict__ bq,
                const ushort* __restrict__ K, const ushort* __restrict__ VT,
                ushort* __restrict__ AO, const int* __restrict__ flagp,
                int xisbf)
{
    __shared__ ushort pool[24576];          // 48 KB

    const int f   = *flagp;
    const int fx  = xisbf ? 0 : f;          // x/Wq dtype in THIS dispatch
    const int bh  = blockIdx.x;
    const int h   = bh & 15, b_ = bh >> 4;
    const int q0  = blockIdx.y * 128;
    const int tid  = threadIdx.x;
    const int lane = tid & 63;
    const int wave = tid >> 6;
    const int qg   = wave >> 1;             // q-group: owns q rows qg*32..+31
    const int kh   = wave & 1;              // key half: keys kh*32..+31 of tile
    const int r15  = lane & 15;
    const int quad = lane >> 4;
    const size_t base = (size_t)bh << 17;

    const int srow = tid >> 3;
    const int sg   = tid & 7;

    // ---- early prefetch: flash tile 0 ----
    uint4 kpre = *(const uint4*)(K  + base + (size_t)srow * 64   + sg * 8);
    uint4 vpre = *(const uint4*)(VT + base + (size_t)srow * 2048 + sg * 8);

    // ---------------- Phase 1: Q tile (128 q x 64 d), pipelined ----------
    floatx4 qacc[4];
#pragma unroll
    for (int db = 0; db < 4; db++) qacc[db] = (floatx4){0.f,0.f,0.f,0.f};

    uint4 xpre[2], wpre;
#pragma unroll
    for (int p = 0; p < 2; p++)
        xpre[p] = load8bf(x, (size_t)(b_ * 2048 + q0 + srow + p * 64) * 1024
                              + sg * 8, fx);
    wpre = load8bf(Wq, (size_t)(h * 64 + srow) * 1024 + sg * 8, fx);

    for (int kb = 0; kb < 1024; kb += 64) {
        int buf = (kb >> 6) & 1;
        ushort* xs  = pool + buf * 8192;
        ushort* wsm = pool + 16384 + buf * 4096;
#pragma unroll
        for (int p = 0; p < 2; p++) {
            int row = srow + p * 64;
            *(uint4*)(&xs[row * 64 + ((sg ^ (row & 7)) << 3)]) = xpre[p];
        }
        *(uint4*)(&wsm[srow * 64 + ((sg ^ (srow & 7)) << 3)]) = wpre;
        __syncthreads();
        if (kb + 64 < 1024) {
#pragma unroll
            for (int p = 0; p < 2; p++)
                xpre[p] = load8bf(x, (size_t)(b_ * 2048 + q0 + srow + p * 64) * 1024
                                      + kb + 64 + sg * 8, fx);
            wpre = load8bf(Wq, (size_t)(h * 64 + srow) * 1024 + kb + 64 + sg * 8, fx);
        }
#pragma unroll
        for (int ks = 0; ks < 2; ks++) {
            int arow = wave * 16 + r15;
            short8 af = *(const short8*)(
                &xs[arow * 64 + (((ks * 4 + quad) ^ (arow & 7)) << 3)]);
#pragma unroll
            for (int db = 0; db < 4; db++) {
                int brow = db * 16 + r15;
                short8 bv = *(const short8*)(
                    &wsm[brow * 64 + (((ks * 4 + quad) ^ (brow & 7)) << 3)]);
                qacc[db] = __builtin_amdgcn_mfma_f32_16x16x32_bf16(
                    af, bv, qacc[db], 0, 0, 0);
            }
        }
    }

    // Qs overlays xs0 (last compute used xs1; own-wave rows only)
    ushort* Qs = pool;
    const float csc = 0.1803368801f;        // log2(e)/8
#pragma unroll
    for (int db = 0; db < 4; db++) {
        int d = db * 16 + r15;
        float bias = loadScalar(bq, h * 64 + d, f);
#pragma unroll
        for (int r = 0; r < 4; r++) {
            int q = wave * 16 + quad * 4 + r;
            Qs[q * 64 + (((d >> 3) ^ (q & 7)) << 3) + (d & 7)] =
                f2bf((qacc[db][r] + bias) * csc);
        }
    }
    __syncthreads();   // Qs visible to all waves (ownership remap)
    short8 qf2[2][2];
#pragma unroll
    for (int qb = 0; qb < 2; qb++)
#pragma unroll
        for (int ks = 0; ks < 2; ks++) {
            int arow = qg * 32 + qb * 16 + r15;
            qf2[qb][ks] = *(const short8*)(
                &Qs[arow * 64 + (((ks * 4 + quad) ^ (arow & 7)) << 3)]);
        }
    __syncthreads();   // qf2 loaded before pool reuse

    // ---------------- Phase 2: flash loop (1 barrier / tile) -------------
    floatx4 oacc[2][4], lacc[2];
#pragma unroll
    for (int qb = 0; qb < 2; qb++) {
#pragma unroll
        for (int db = 0; db < 4; db++) oacc[qb][db] = (floatx4){0.f,0.f,0.f,0.f};
        lacc[qb] = (floatx4){0.f,0.f,0.f,0.f};
    }
    short8 ones;
#pragma unroll
    for (int j = 0; j < 8; j++) ones[j] = (short)0x3F80;

    for (int t0 = 0; t0 < 2048; t0 += 64) {
        int buf = (t0 >> 6) & 1;
        ushort* Ks = pool + buf * 4096;
        ushort* Vt = pool + 8192 + buf * 4096;
        *(uint4*)(&Ks[srow * 64 + ((sg ^ (srow & 7)) << 3)]) = kpre;
        *(uint4*)(&Vt[srow * 64 + ((sg ^ (srow & 7)) << 3)]) = vpre;
        __syncthreads();
        if (t0 < 1984) {
            kpre = *(const uint4*)(K  + base + (size_t)(t0 + 64 + srow) * 64
                                       + sg * 8);
            vpre = *(const uint4*)(VT + base + (size_t)srow * 2048
                                       + t0 + 64 + sg * 8);
        }

        // S^T = K Q^T : rows = own 32 keys (kh half), cols = own 32 queries
        floatx4 s[2][2];
#pragma unroll
        for (int mb = 0; mb < 2; mb++)
#pragma unroll
            for (int qb = 0; qb < 2; qb++) s[mb][qb] = (floatx4){0.f,0.f,0.f,0.f};
#pragma unroll
        for (int ks = 0; ks < 2; ks++)
#pragma unroll
            for (int mb = 0; mb < 2; mb++) {
                int arow = kh * 32 + mb * 16 + r15;
                short8 kf = *(const short8*)(
                    &Ks[arow * 64 + (((ks * 4 + quad) ^ (arow & 7)) << 3)]);
#pragma unroll
                for (int qb = 0; qb < 2; qb++)
                    s[mb][qb] = __builtin_amdgcn_mfma_f32_16x16x32_bf16(
                        kf, qf2[qb][ks], s[mb][qb], 0, 0, 0);
            }

        // P = 2^S, truncation-packed bf16 pairs in-register
        uint Lr[2][2], Hr[2][2];
#pragma unroll
        for (int mb = 0; mb < 2; mb++)
#pragma unroll
            for (int qb = 0; qb < 2; qb++) {
                uint b0 = __builtin_bit_cast(uint, __builtin_amdgcn_exp2f(s[mb][qb][0]));
                uint b1 = __builtin_bit_cast(uint, __builtin_amdgcn_exp2f(s[mb][qb][1]));
                uint b2 = __builtin_bit_cast(uint, __builtin_amdgcn_exp2f(s[mb][qb][2]));
                uint b3 = __builtin_bit_cast(uint, __builtin_amdgcn_exp2f(s[mb][qb][3]));
                Lr[mb][qb] = (b1 & 0xFFFF0000u) | (b0 >> 16);
                Hr[mb][qb] = (b3 & 0xFFFF0000u) | (b2 >> 16);
            }
        // Quad-transpose via permlane{32,16}_swap (R18-verified mapping)
        short8 pf[2];
#pragma unroll
        for (int qb = 0; qb < 2; qb++) {
            uint2v tL = __builtin_amdgcn_permlane32_swap(
                Lr[0][qb], Lr[1][qb], false, false);
            uint2v uL = __builtin_amdgcn_permlane16_swap(
                tL[0], tL[1], false, false);
            uint2v tH = __builtin_amdgcn_permlane32_swap(
                Hr[0][qb], Hr[1][qb], false, false);
            uint2v uH = __builtin_amdgcn_permlane16_swap(
                tH[0], tH[1], false, false);
            union { uint u[4]; short8 s8; } pk;
            pk.u[0] = uL[0]; pk.u[1] = uH[0]; pk.u[2] = uL[1]; pk.u[3] = uH[1];
            pf[qb] = pk.s8;
        }

        // O += P V^T (own key half = k-slice kh), l += P·1
#pragma unroll
        for (int db = 0; db < 4; db++) {
            int brow = db * 16 + r15;
            short8 vf = *(const short8*)(
                &Vt[brow * 64 + (((kh * 4 + quad) ^ (brow & 7)) << 3)]);
#pragma unroll
            for (int qb = 0; qb < 2; qb++)
                oacc[qb][db] = __builtin_amdgcn_mfma_f32_16x16x32_bf16(
                    pf[qb], vf, oacc[qb][db], 0, 0, 0);
        }
#pragma unroll
        for (int qb = 0; qb < 2; qb++)
            lacc[qb] = __builtin_amdgcn_mfma_f32_16x16x32_bf16(
                pf[qb], ones, lacc[qb], 0, 0, 0);
    }

    // ---- kh-pair reduction (f32, via LDS) + epilogue -> AO ----
    __syncthreads();
    {
        char* rb = (char*)pool + qg * 10240 + lane * 16;
        if (kh) {
#pragma unroll
            for (int qb = 0; qb < 2; qb++) {
#pragma unroll
                for (int db = 0; db < 4; db++)
                    *(floatx4*)(rb + (qb * 4 + db) * 1024) = oacc[qb][db];
                *(floatx4*)(rb + (8 + qb) * 1024) = lacc[qb];
            }
        }
        __syncthreads();
        if (!kh) {
#pragma unroll
            for (int qb = 0; qb < 2; qb++) {
#pragma unroll
                for (int db = 0; db < 4; db++)
                    oacc[qb][db] += *(const floatx4*)(rb + (qb * 4 + db) * 1024);
                lacc[qb] += *(const floatx4*)(rb + (8 + qb) * 1024);
            }
            float inv[2][4];
#pragma unroll
            for (int qb = 0; qb < 2; qb++)
#pragma unroll
                for (int r = 0; r < 4; r++) inv[qb][r] = 1.f / lacc[qb][r];
#pragma unroll
            for (int qb = 0; qb < 2; qb++)
#pragma unroll
                for (int db = 0; db < 4; db++) {
                    int d = db * 16 + r15;
#pragma unroll
                    for (int r = 0; r < 4; r++) {
                        int qi = q0 + qg * 32 + qb * 16 + quad * 4 + r;
                        AO[((size_t)(b_ * 2048 + qi) << 10) + h * 64 + d] =
                            f2bf(oacc[qb][db][r] * inv[qb][r]);
                    }
                }
        }
    }
}

__global__ void copy_u4(const uint4* __restrict__ src, uint4* __restrict__ dst) {
    size_t i = (size_t)blockIdx.x * 256 + threadIdx.x;
    dst[i] = src[i];
}

// ---------------------------------------------------------------------------
extern "C" void kernel_launch(void* const* d_in, const int* in_sizes, int n_in,
                              void* d_out, int out_size, void* d_ws, size_t ws_size,
                              hipStream_t stream)
{
    const void* x  = d_in[0];
    const void* Wq = d_in[1];
    const void* bq = d_in[2];
    const void* Wk = d_in[3];
    const void* bk = d_in[4];
    const void* Wv = d_in[5];
    const void* bv = d_in[6];
    const void* Wo = d_in[7];
    const void* bo = d_in[8];

    const size_t TEN = (size_t)2 * 16 * 2048 * 64;   // 4 Mi elements (8 MB)
    const size_t M1  = (size_t)1 << 20;
    int*    flagp = (int*)d_ws;
    ushort* Kw    = (ushort*)((char*)d_ws + 256);
    ushort* Vw    = Kw + TEN;

    // ws tiers:
    //   >= 40.25 MB : cvt path + AOw in ws
    //   >= 32.25 MB : cvt path, AOw = d_out (+copy dance)
    //   >= 24.25 MB : legacy big_ws path
    //   else        : legacy small_ws path
    const size_t need_cvt = 256 + (2 * TEN + 8 * M1) * sizeof(ushort);
    const size_t need_aow = need_cvt + TEN * sizeof(ushort);

    detect_dtype<<<1, 256, 0, stream>>>((const ushort*)x, flagp);

    if (ws_size >= need_cvt) {
        ushort* CV  = Vw + TEN;
        ushort* xb  = CV;
        ushort* wqb = CV + 4 * M1;
        ushort* wkb = CV + 5 * M1;
        ushort* wvb = CV + 6 * M1;
        ushort* wob = CV + 7 * M1;
        const bool aow_ws = ws_size >= need_aow;
        ushort* AOw = aow_ws ? (CV + 8 * M1) : (ushort*)d_out;
        ushort* Oin = aow_ws ? AOw : Kw;

        // one-shot bf16 conversion of x + all weights (8 Mi elems)
        cvt_bf16<<<dim3(4096), dim3(256), 0, stream>>>(
            x, Wq, Wk, Wv, Wo, CV, flagp);

        // K AND V in ONE dual-N dispatch: half-a = Wk -> Kw (pm=1),
        // half-b = Wv -> Vw (pm=2, V^T).  Grid 32x16 = 512 blocks.
        gemm_dual<<<dim3(32, 16), dim3(512), 0, stream>>>(
            xb, wkb, wvb, bk, bv, Kw, Vw, /*pa=*/1, /*pb=*/2,
            /*nb_off=*/0, /*out_ext=*/0, flagp);

        // fused Q-proj + attention (bf16 x/Wq)
        attn_fused<<<dim3(32, 16), dim3(512), 0, stream>>>(
            xb, wqb, bq, Kw, Vw, AOw, flagp, /*xisbf=*/1);

        if (!aow_ws)
            copy_u4<<<dim3(2048), dim3(256), 0, stream>>>(
                (const uint4*)d_out, (uint4*)Oin);

        // O-projection: both halves from Wo (cols [0,512) and [512,1024)).
        gemm_dual<<<dim3(32, 8), dim3(512), 0, stream>>>(
            Oin, wob, wob, bo, bo, d_out, d_out, /*pa=*/0, /*pb=*/0,
            /*nb_off=*/512, /*out_ext=*/1, flagp);
    } else {
        const bool big_ws = ws_size >= 3 * TEN * sizeof(ushort) + 256;
        ushort* AOw = big_ws ? (Vw + TEN) : (ushort*)d_out;
        ushort* Oin = big_ws ? AOw : Kw;

        gemm_bt<128><<<dim3(32, 16, 2), dim3(512), 0, stream>>>(
            x, Wk, Wv, bk, bv, Kw, Vw, 1, 2, 1, 0, flagp);
        attn_fused<<<dim3(32, 16), dim3(512), 0, stream>>>(
            x, Wq, bq, Kw, Vw, AOw, flagp, /*xisbf=*/0);
        if (!big_ws)
            copy_u4<<<dim3(2048), dim3(256), 0, stream>>>(
                (const uint4*)d_out, (uint4*)Oin);
        gemm_bt<128><<<dim3(32, 16, 1), dim3(512), 0, stream>>>(
            Oin, Wo, Wo, bo, bo, d_out, d_out, 0, 0, 0, 1, flagp);
    }
}